// Round 6
// baseline (610.367 us; speedup 1.0000x reference)
//
#include <hip/hip_runtime.h>
#include <math.h>

#define SEQ 2048
#define CDIM 1536
#define HN 8
#define DVC 192
#define BN 2
#define NPOS 4095   // 2*SEQ-1
#define HDK 512     // H*DK
#define HDV 1536    // H*DV
#define PSTR 72     // Pbs LDS stride in halfs (144B: 16B-aligned rows, balanced banks)

typedef __attribute__((ext_vector_type(8))) _Float16 hf8v;  // 8 f16 (4 VGPRs)
typedef __attribute__((ext_vector_type(4))) _Float16 hf4v;  // 4 f16 (b64)
typedef __attribute__((ext_vector_type(4))) float f4v;      // MFMA C/D frag

static __device__ __forceinline__ f4v mfma16(hf8v a, hf8v b, f4v c) {
  return __builtin_amdgcn_mfma_f32_16x16x32_f16(a, b, c, 0, 0, 0);
}
static __device__ __forceinline__ void gl2lds16(const void* g, void* l) {
  __builtin_amdgcn_global_load_lds((const __attribute__((address_space(1))) unsigned int*)g,
                                   (__attribute__((address_space(3))) unsigned int*)l,
                                   16, 0, 0);
}

// ================= fused prep: pos-features + cast x + 5 weight transposes =================
#define PF_B   512
#define CAST_B 6144
#define TWQ_B  768
#define TWK_B  768
#define TWV_B  2304
#define TWO_B  2304
#define TWR_B  96
#define PREP_BLOCKS (PF_B + CAST_B + TWQ_B + TWK_B + TWV_B + TWO_B + TWR_B)

__device__ __forceinline__ void twc_tile(const float* __restrict__ W, _Float16* __restrict__ WT,
                                         int K, int N, int tile, float (*tls)[33], int tid) {
  int ntn = N >> 5;
  int nt = tile % ntn, kt = tile / ntn;
  int k0 = kt * 32, n0 = nt * 32;
  int tx = tid & 31, ty = tid >> 5;
#pragma unroll
  for (int p = 0; p < 4; p++) tls[ty + p * 8][tx] = W[(size_t)(k0 + ty + p * 8) * N + n0 + tx];
  __syncthreads();
#pragma unroll
  for (int p = 0; p < 4; p++) {
    int n = ty + p * 8;
    WT[(size_t)(n0 + n) * K + k0 + tx] = (_Float16)tls[tx][n];
  }
}

__global__ __launch_bounds__(256) void prep_kernel(
    const float* __restrict__ x, const float* __restrict__ Wq, const float* __restrict__ Wk,
    const float* __restrict__ Wv, const float* __restrict__ Wo, const float* __restrict__ Wr,
    float* __restrict__ pe_raw, unsigned* __restrict__ gmax, _Float16* __restrict__ xb,
    _Float16* __restrict__ WTqkv, _Float16* __restrict__ WoT, _Float16* __restrict__ WrT) {
  __shared__ float tls[32][33];
  int blk = blockIdx.x, tid = threadIdx.x;
  if (blk < PF_B) {
    int j = blk >> 4;
    int pos = (blk & 15) * 256 + tid;
    float prob = 0.0f;
    if (pos < NPOS) {
      float ap = fabsf((float)(pos - (SEQ - 1)));
      float hl = exp2f(3.0f + 8.0f * (float)j / 31.0f);
      float fe = exp2f(-ap / hl);
      float cw = exp2f((float)(j + 1)) - 1.0f;
      float fc = (cw > ap) ? 1.0f : 0.0f;
      float conc = 4.0f * (float)((j + 1) * (j + 1));
      float rate = (float)(j + 1) / 16.0f;
      float log_norm = lgammaf(conc) - conc * logf(rate);
      float log_un = (conc - 1.0f) * logf(ap) - rate * ap;
      prob = expf(log_un - log_norm) + 1e-8f;
      pe_raw[pos * 96 + j] = fe;
      pe_raw[pos * 96 + 32 + j] = fc;
      pe_raw[pos * 96 + 64 + j] = prob;
    }
    float m = prob;
#pragma unroll
    for (int off = 32; off > 0; off >>= 1) m = fmaxf(m, __shfl_down(m, off));
    __shared__ float red[4];
    if ((tid & 63) == 0) red[tid >> 6] = m;
    __syncthreads();
    if (tid == 0) {
      m = fmaxf(fmaxf(red[0], red[1]), fmaxf(red[2], red[3]));
      atomicMax(&gmax[j], __float_as_uint(m));
    }
  } else if (blk < PF_B + CAST_B) {
    int i = ((blk - PF_B) * 256 + tid) * 4;
    float4 v = *(const float4*)(x + i);
    _Float16 o[4] = {(_Float16)v.x, (_Float16)v.y, (_Float16)v.z, (_Float16)v.w};
    *(unsigned long long*)(xb + i) = *(const unsigned long long*)o;
  } else if (blk < PF_B + CAST_B + TWQ_B) {
    twc_tile(Wq, WTqkv + 0 * (size_t)CDIM, CDIM, HDK, blk - (PF_B + CAST_B), tls, tid);
  } else if (blk < PF_B + CAST_B + TWQ_B + TWK_B) {
    twc_tile(Wk, WTqkv + 512 * (size_t)CDIM, CDIM, HDK, blk - (PF_B + CAST_B + TWQ_B), tls, tid);
  } else if (blk < PF_B + CAST_B + TWQ_B + TWK_B + TWV_B) {
    twc_tile(Wv, WTqkv + 1024 * (size_t)CDIM, CDIM, HDV, blk - (PF_B + CAST_B + TWQ_B + TWK_B), tls, tid);
  } else if (blk < PF_B + CAST_B + TWQ_B + TWK_B + TWV_B + TWO_B) {
    twc_tile(Wo, WoT, CDIM, HDV, blk - (PF_B + CAST_B + TWQ_B + TWK_B + TWV_B), tls, tid);
  } else {
    twc_tile(Wr, WrT, 192, HDK, blk - (PF_B + CAST_B + TWQ_B + TWK_B + TWV_B + TWO_B), tls, tid);
  }
}

// ============ pe [4096][192] fp16: normalize gamma, apply sign-concat ============
__global__ __launch_bounds__(256) void pe_norm_kernel(const float* __restrict__ pe_raw,
                                                      const unsigned* __restrict__ gmax,
                                                      _Float16* __restrict__ pe_h) {
  int idx = blockIdx.x * 256 + threadIdx.x;  // over 4096*96
  int pos = idx / 96, f = idx - pos * 96;
  float val = 0.0f, sval = 0.0f;
  if (pos < NPOS) {
    val = pe_raw[pos * 96 + f];
    if (f >= 64) val *= 1.0f / __uint_as_float(gmax[f - 64]);
    float sgn = (pos > SEQ - 1) ? 1.0f : ((pos < SEQ - 1) ? -1.0f : 0.0f);
    sval = sgn * val;
  }
  pe_h[pos * 192 + f] = (_Float16)val;
  pe_h[pos * 192 + 96 + f] = (_Float16)sval;
}

// ================= fp16 MFMA GEMM, 128x128xBK32, XOR-swizzled LDS =================
// MODE 0 (QKV): c<512 -> qb*0.125 ; c<1024 -> kb[B,H,S,64] ; else vtb[B,H,192,S] PI-PERMUTED
// MODE 1 (RK):  rkb[(h*4096+pos)*64+d]
// MODE 2 (OUT): fp32 out + bias
template <int MODE>
__global__ __launch_bounds__(256, 2) void mfma_gemm(
    const _Float16* __restrict__ A, const _Float16* __restrict__ B,
    const float* __restrict__ bias, void* __restrict__ out0, void* __restrict__ out1,
    void* __restrict__ out2, int K) {
  __shared__ __align__(16) _Float16 As[128 * 32];
  __shared__ __align__(16) _Float16 Bs[128 * 32];
  const int tid = threadIdx.x;
  const int lane = tid & 63, l15 = lane & 15, quad = lane >> 4;
  const int wv = tid >> 6;
  const int wm = (wv & 1) * 64, wn = (wv >> 1) * 64;
  const int row0 = blockIdx.y * 128, col0 = blockIdx.x * 128;
  f4v acc[4][4];
#pragma unroll
  for (int i = 0; i < 4; i++)
#pragma unroll
    for (int j = 0; j < 4; j++) acc[i][j] = (f4v)0.0f;

  for (int k0 = 0; k0 < K; k0 += 32) {
    __syncthreads();
#pragma unroll
    for (int p = 0; p < 2; p++) {
      int idx = tid + p * 256;
      int rr = idx >> 2, sc = idx & 3;
      int gc = (sc ^ ((rr >> 1) & 3)) << 3;
      gl2lds16(A + (size_t)(row0 + rr) * K + k0 + gc, As + idx * 8);
      gl2lds16(B + (size_t)(col0 + rr) * K + k0 + gc, Bs + idx * 8);
    }
    __syncthreads();
    hf8v af[4], bfr[4];
#pragma unroll
    for (int t = 0; t < 4; t++) {
      int lrA = wm + t * 16 + l15;
      int lrB = wn + t * 16 + l15;
      af[t] = *(const hf8v*)(As + lrA * 32 + ((quad ^ ((lrA >> 1) & 3)) << 3));
      bfr[t] = *(const hf8v*)(Bs + lrB * 32 + ((quad ^ ((lrB >> 1) & 3)) << 3));
    }
#pragma unroll
    for (int mt = 0; mt < 4; mt++)
#pragma unroll
      for (int nt = 0; nt < 4; nt++)
        acc[mt][nt] = mfma16(af[mt], bfr[nt], acc[mt][nt]);
  }
#pragma unroll
  for (int mt = 0; mt < 4; mt++)
#pragma unroll
    for (int reg = 0; reg < 4; reg++) {
      int r = row0 + wm + mt * 16 + quad * 4 + reg;
      int bb = r >> 11, ss = r & (SEQ - 1);
#pragma unroll
      for (int nt = 0; nt < 4; nt++) {
        int c = col0 + wn + nt * 16 + l15;
        float vv = acc[mt][nt][reg];
        if (MODE == 0) {
          if (c < 512) {
            ((_Float16*)out0)[(size_t)r * HDK + c] = (_Float16)(vv * 0.125f);
          } else if (c < 1024) {
            int cc = c - 512, h = cc >> 6, d = cc & 63;
            ((_Float16*)out1)[(((size_t)bb * HN + h) * SEQ + ss) * 64 + d] = (_Float16)vv;
          } else {
            int cc = c - 1024, h = cc / DVC, e = cc - h * DVC;
            // pi-permute key within its 64-block: key k -> pos (k&15)*4 + ((k>>4)&3)
            int jp = (ss & ~63) | ((ss & 15) << 2) | ((ss >> 4) & 3);
            ((_Float16*)out2)[(((size_t)bb * HN + h) * DVC + e) * SEQ + jp] = (_Float16)vv;
          }
        } else if (MODE == 1) {
          int h = c >> 6, d = c & 63;
          ((_Float16*)out0)[((size_t)h * 4096 + r) * 64 + d] = (_Float16)vv;
        } else {
          ((float*)out0)[(size_t)r * HDV + c] = vv + bias[c];
        }
      }
    }
}

// ================= flash MFMA attention: K/V frags from global, RK ring, 1 barrier/iter =====
// grid (16, SPLITKV?32:16); 4 waves, wave w owns q-rows [i0+32w, i0+32w+32) as 2 strips of 16
template <bool SPLITKV>
__global__ __launch_bounds__(256, 3) void attn_mfma(
    const _Float16* __restrict__ qb, const _Float16* __restrict__ kb,
    const _Float16* __restrict__ vtb, const _Float16* __restrict__ rkb,
    const float* __restrict__ rwb, const int* __restrict__ mask,
    _Float16* __restrict__ attn_out, float* __restrict__ Opart, float* __restrict__ ml) {
  __shared__ __align__(16) _Float16 RKring[256 * 64];  // 32768 B rolling window
  __shared__ __align__(16) _Float16 Pbs[128 * PSTR];   // 18432 B, wave-private P
  // total 51.2 KB -> 3 blocks/CU

  const int i0 = blockIdx.x * 128;
  const int by = blockIdx.y;
  const int bh = SPLITKV ? (by & 15) : by;
  const int half = SPLITKV ? (by >> 4) : 0;
  const int b = bh >> 3, h = bh & 7;
  const int tid = threadIdx.x;
  const int wv = tid >> 6, lane = tid & 63;
  const int l15 = lane & 15, quad = lane >> 4;
  const _Float16* rkh = rkb + (size_t)h * 4096 * 64;

  // Q A-fragments, 2 strips (held in VGPRs across all key tiles)
  hf8v qf[2][2], qbf[2][2];
#pragma unroll
  for (int s = 0; s < 2; s++) {
    int qrow = i0 + wv * 32 + s * 16 + l15;
    const _Float16* qp = qb + (size_t)(b * SEQ + qrow) * HDK + h * 64;
#pragma unroll
    for (int kc = 0; kc < 2; kc++) {
      hf8v qv = *(const hf8v*)(qp + kc * 32 + quad * 8);
      qf[s][kc] = qv;
      hf8v t;
#pragma unroll
      for (int j = 0; j < 8; j++)
        t[j] = (_Float16)((float)qv[j] + rwb[h * 64 + kc * 32 + quad * 8 + j]);
      qbf[s][kc] = t;
    }
  }

  f4v Of[2][12];
#pragma unroll
  for (int s = 0; s < 2; s++)
#pragma unroll
    for (int se = 0; se < 12; se++) Of[s][se] = (f4v)0.0f;
  float m_i[2][4] = {{-INFINITY, -INFINITY, -INFINITY, -INFINITY},
                     {-INFINITY, -INFINITY, -INFINITY, -INFINITY}};
  float l_i[2][4] = {{0.f, 0.f, 0.f, 0.f}, {0.f, 0.f, 0.f, 0.f}};  // per-lane partials

  const int j0beg = SPLITKV ? half * (SEQ / 2) : 0;
  const int j0end = SPLITKV ? j0beg + SEQ / 2 : SEQ;
  const int base0 = j0beg - i0 + 1920;  // multiple of 64, >= 0

  // prologue: stage 192-row window [base0, base0+192) into ring
#pragma unroll
  for (int r = 0; r < 6; r++) {
    int idx = tid + r * 256;
    int rowl = idx >> 3, sc = idx & 7;
    int g = base0 + rowl;
    int phys = g & 255;
    gl2lds16(rkh + (size_t)g * 64 + ((sc ^ (g & 7)) << 3), RKring + (phys << 6) + (sc << 3));
  }
  __syncthreads();

  for (int j0 = j0beg; j0 < j0end; j0 += 64) {
    const int base = j0 - i0 + 1920;
    // prefetch next iter's 64 new rows [base+192, base+256) (slots dead since last iter)
    if (j0 + 64 < j0end) {
#pragma unroll
      for (int r = 0; r < 2; r++) {
        int idx = tid + r * 256;
        int rowl = idx >> 3, sc = idx & 7;
        int g = base + 192 + rowl;
        int phys = g & 255;
        gl2lds16(rkh + (size_t)g * 64 + ((sc ^ (g & 7)) << 3), RKring + (phys << 6) + (sc << 3));
      }
    }
    float mv[4];
#pragma unroll
    for (int st = 0; st < 4; st++)
      mv[st] = mask[b * SEQ + j0 + st * 16 + l15] ? 0.f : -1e9f;

#pragma unroll
    for (int s = 0; s < 2; s++) {
      // content logits: K B-frags straight from global (L1-cached, shared by 4 waves)
      f4v Sf[4];
#pragma unroll
      for (int st = 0; st < 4; st++) {
        Sf[st] = (f4v)0.0f;
#pragma unroll
        for (int kc = 0; kc < 2; kc++) {
          hf8v kf = *(const hf8v*)(kb + ((size_t)bh * SEQ + j0 + st * 16 + l15) * 64 +
                                   kc * 32 + quad * 8);
          Sf[st] = mfma16(qf[s][kc], kf, Sf[st]);
        }
      }
      // rel logits over 80-row window from the ring
      f4v Rf[5];
      const int tb = 112 - 32 * wv - 16 * s;
#pragma unroll
      for (int u = 0; u < 5; u++) {
        Rf[u] = (f4v)0.0f;
#pragma unroll
        for (int kc = 0; kc < 2; kc++) {
          int g = base + tb + u * 16 + l15;
          int phys = g & 255;
          hf8v rf = *(const hf8v*)(RKring + (phys << 6) +
                                   ((((kc << 2) | quad) ^ (phys & 7)) << 3));
          Rf[u] = mfma16(qbf[s][kc], rf, Rf[u]);
        }
      }
      // band extraction via bpermute: S[r][c] += R[r][c-r+15]
#pragma unroll
      for (int reg = 0; reg < 4; reg++) {
        int delta = l15 - (quad << 2) - reg + 15;  // [0,30]
        int srcl = (quad << 4) | (delta & 15);
        float sh0 = __shfl(Rf[0][reg], srcl, 64);
        float sh1 = __shfl(Rf[1][reg], srcl, 64);
        float sh2 = __shfl(Rf[2][reg], srcl, 64);
        float sh3 = __shfl(Rf[3][reg], srcl, 64);
        float sh4 = __shfl(Rf[4][reg], srcl, 64);
        bool hib = delta >= 16;
        Sf[0][reg] += (hib ? sh1 : sh0) + mv[0];
        Sf[1][reg] += (hib ? sh2 : sh1) + mv[1];
        Sf[2][reg] += (hib ? sh3 : sh2) + mv[2];
        Sf[3][reg] += (hib ? sh4 : sh3) + mv[3];
      }
      // online softmax; P packed to b64 via pi-slots (slot = col15*4 + st <-> key col15+16*st)
#pragma unroll
      for (int reg = 0; reg < 4; reg++) {
        float t = fmaxf(fmaxf(Sf[0][reg], Sf[1][reg]), fmaxf(Sf[2][reg], Sf[3][reg]));
        t = fmaxf(t, __shfl_xor(t, 1));
        t = fmaxf(t, __shfl_xor(t, 2));
        t = fmaxf(t, __shfl_xor(t, 4));
        t = fmaxf(t, __shfl_xor(t, 8));
        float mn = fmaxf(m_i[s][reg], t);
        float alpha = __expf(m_i[s][reg] - mn);
        m_i[s][reg] = mn;
        if (__ballot(alpha != 1.0f)) {
          l_i[s][reg] *= alpha;
#pragma unroll
          for (int se = 0; se < 12; se++) Of[s][se][reg] *= alpha;
        }
        hf4v pv;
        float rs = 0.f;
#pragma unroll
        for (int st = 0; st < 4; st++) {
          float p = __expf(Sf[st][reg] - mn);
          rs += p;
          pv[st] = (_Float16)p;
        }
        l_i[s][reg] += rs;  // per-lane partial; row-reduce in epilogue
        *(hf4v*)(Pbs + (size_t)(wv * 32 + s * 16 + quad * 4 + reg) * PSTR + l15 * 4) = pv;
      }
    }

    // PV: P A-frags (wave-private LDS, in-order DS), V B-frags from global (pi-ordered vtb)
    hf8v pa[2][2];
#pragma unroll
    for (int s = 0; s < 2; s++)
#pragma unroll
      for (int kc = 0; kc < 2; kc++)
        pa[s][kc] = *(const hf8v*)(Pbs + (size_t)(wv * 32 + s * 16 + l15) * PSTR +
                                   kc * 32 + quad * 8);
#pragma unroll
    for (int se = 0; se < 12; se++) {
#pragma unroll
      for (int kc = 0; kc < 2; kc++) {
        hf8v vf = *(const hf8v*)(vtb + ((size_t)bh * DVC + se * 16 + l15) * SEQ + j0 +
                                 kc * 32 + quad * 8);
        Of[0][se] = mfma16(pa[0][kc], vf, Of[0][se]);
        Of[1][se] = mfma16(pa[1][kc], vf, Of[1][se]);
      }
    }
    __syncthreads();  // readers of ring rows [base,base+64) done; next prefetch may overwrite
  }

#pragma unroll
  for (int s = 0; s < 2; s++)
#pragma unroll
    for (int reg = 0; reg < 4; reg++) {
      float ls = l_i[s][reg];
      ls += __shfl_xor(ls, 1);
      ls += __shfl_xor(ls, 2);
      ls += __shfl_xor(ls, 4);
      ls += __shfl_xor(ls, 8);
      int row = i0 + wv * 32 + s * 16 + quad * 4 + reg;
      int rg = b * SEQ + row;
      if constexpr (SPLITKV) {
        float* Op = Opart + ((size_t)(half * 4096 + rg)) * HDV + h * DVC;
#pragma unroll
        for (int se = 0; se < 12; se++) Op[se * 16 + l15] = Of[s][se][reg];
        if (l15 == 0) {
          size_t mlb = (((size_t)half * 4096 + rg) * HN + h) * 2;
          ml[mlb] = m_i[s][reg];
          ml[mlb + 1] = ls;
        }
      } else {
        float inv = 1.0f / ls;
        size_t base2 = (size_t)rg * HDV + h * DVC;
#pragma unroll
        for (int se = 0; se < 12; se++)
          attn_out[base2 + se * 16 + l15] = (_Float16)(Of[s][se][reg] * inv);
      }
    }
}

// ================= combine the two KV halves =================
__global__ __launch_bounds__(256) void combine_kernel(const float* __restrict__ Opart,
                                                      const float* __restrict__ ml,
                                                      _Float16* __restrict__ attn_out) {
  int i4 = blockIdx.x * 256 + threadIdx.x;  // over 4096*384
  int rg = i4 / 384, c4 = (i4 - rg * 384) * 4;
  int h = c4 / DVC;
  size_t mlb0 = ((size_t)rg * HN + h) * 2;
  size_t mlb1 = (((size_t)4096 + rg) * HN + h) * 2;
  float m0 = ml[mlb0], l0 = ml[mlb0 + 1];
  float m1 = ml[mlb1], l1 = ml[mlb1 + 1];
  float M = fmaxf(m0, m1);
  float w0 = __expf(m0 - M), w1 = __expf(m1 - M);
  float inv = 1.0f / (l0 * w0 + l1 * w1);
  float4 O0 = *(const float4*)(Opart + (size_t)rg * HDV + c4);
  float4 O1 = *(const float4*)(Opart + ((size_t)4096 + rg) * HDV + c4);
  _Float16 o[4] = {(_Float16)((O0.x * w0 + O1.x * w1) * inv),
                   (_Float16)((O0.y * w0 + O1.y * w1) * inv),
                   (_Float16)((O0.z * w0 + O1.z * w1) * inv),
                   (_Float16)((O0.w * w0 + O1.w * w1) * inv)};
  *(unsigned long long*)(attn_out + (size_t)rg * HDV + c4) = *(const unsigned long long*)o;
}

extern "C" void kernel_launch(void* const* d_in, const int* in_sizes, int n_in,
                              void* d_out, int out_size, void* d_ws, size_t ws_size,
                              hipStream_t stream) {
  const float* x    = (const float*)d_in[0];
  const int*   mask = (const int*)d_in[1];
  const float* Wq   = (const float*)d_in[2];
  const float* Wk   = (const float*)d_in[3];
  const float* Wv   = (const float*)d_in[4];
  const float* Wr   = (const float*)d_in[5];
  const float* rwb  = (const float*)d_in[6];
  const float* Wo   = (const float*)d_in[7];
  const float* bo   = (const float*)d_in[8];
  float* out = (float*)d_out;

  char* wsb = (char*)d_ws;
  size_t o = 0;
  auto al = [](size_t v) { return (v + 255) & ~(size_t)255; };
#define CARVE(ptr_t, name, bytes) ptr_t name = (ptr_t)(wsb + o); o = al(o + (bytes));
  CARVE(float*, pe_raw, (size_t)4096 * 96 * 4)
  CARVE(unsigned*, gmax, 128)
  CARVE(_Float16*, pe_h, (size_t)4096 * 192 * 2)
  CARVE(_Float16*, WrT, (size_t)HDK * 192 * 2)
  CARVE(_Float16*, xb, (size_t)BN * SEQ * CDIM * 2)
  CARVE(_Float16*, WTqkv, (size_t)2560 * CDIM * 2)
  CARVE(_Float16*, WoT, (size_t)HDV * CDIM * 2)
  CARVE(_Float16*, qb, (size_t)BN * SEQ * HDK * 2)
  CARVE(_Float16*, kb, (size_t)BN * SEQ * HDK * 2)
  CARVE(_Float16*, vtb, (size_t)BN * SEQ * HDV * 2)
  CARVE(_Float16*, rkb, (size_t)HN * 4096 * 64 * 2)
  _Float16* attnh = xb;  // xb dead after QKV gemm -> safe alias
  CARVE(float*, Opart, (size_t)2 * 4096 * HDV * 4)
  CARVE(float*, ml, (size_t)2 * 4096 * HN * 2 * 4)
  bool dosplit = (o <= ws_size);

  hipMemsetAsync(gmax, 0, 32 * sizeof(unsigned), stream);
  prep_kernel<<<PREP_BLOCKS, 256, 0, stream>>>(x, Wq, Wk, Wv, Wo, Wr, pe_raw, gmax, xb,
                                               WTqkv, WoT, WrT);
  pe_norm_kernel<<<4096 * 96 / 256, 256, 0, stream>>>(pe_raw, gmax, pe_h);
  mfma_gemm<0><<<dim3(2560 / 128, BN * SEQ / 128), 256, 0, stream>>>(
      xb, WTqkv, nullptr, qb, kb, vtb, CDIM);
  mfma_gemm<1><<<dim3(HDK / 128, 4096 / 128), 256, 0, stream>>>(
      pe_h, WrT, nullptr, rkb, nullptr, nullptr, 192);
  if (dosplit) {
    attn_mfma<true><<<dim3(SEQ / 128, 32), 256, 0, stream>>>(qb, kb, vtb, rkb, rwb, mask,
                                                             attnh, Opart, ml);
    combine_kernel<<<4096 * 384 / 256, 256, 0, stream>>>(Opart, ml, attnh);
  } else {
    attn_mfma<false><<<dim3(SEQ / 128, 16), 256, 0, stream>>>(qb, kb, vtb, rkb, rwb, mask,
                                                              attnh, nullptr, nullptr);
  }
  mfma_gemm<2><<<dim3(HDV / 128, BN * SEQ / 128), 256, 0, stream>>>(
      attnh, WoT, bo, out, nullptr, nullptr, CDIM);
}

// Round 7
// 353.925 us; speedup vs baseline: 1.7246x; 1.7246x over previous
//
#include <hip/hip_runtime.h>
#include <math.h>

#define SEQ 2048
#define CDIM 1536
#define HN 8
#define DVC 192
#define BN 2
#define NPOS 4095   // 2*SEQ-1
#define HDK 512     // H*DK
#define HDV 1536    // H*DV
#define PSTR 72     // Pbs LDS stride in halfs (144 B rows: 16B-aligned, 2-way banks max)

typedef __attribute__((ext_vector_type(8))) _Float16 hf8v;  // 8 f16 (4 VGPRs)
typedef __attribute__((ext_vector_type(4))) _Float16 hf4v;  // 4 f16 (b64)
typedef __attribute__((ext_vector_type(4))) float f4v;      // MFMA C/D frag

static __device__ __forceinline__ f4v mfma16(hf8v a, hf8v b, f4v c) {
  return __builtin_amdgcn_mfma_f32_16x16x32_f16(a, b, c, 0, 0, 0);
}
static __device__ __forceinline__ void gl2lds16(const void* g, void* l) {
  __builtin_amdgcn_global_load_lds((const __attribute__((address_space(1))) unsigned int*)g,
                                   (__attribute__((address_space(3))) unsigned int*)l,
                                   16, 0, 0);
}

// ================= fused prep: pos-features + cast x + 5 weight transposes =================
#define PF_B   512
#define CAST_B 6144
#define TWQ_B  768
#define TWK_B  768
#define TWV_B  2304
#define TWO_B  2304
#define TWR_B  96
#define PREP_BLOCKS (PF_B + CAST_B + TWQ_B + TWK_B + TWV_B + TWO_B + TWR_B)

__device__ __forceinline__ void twc_tile(const float* __restrict__ W, _Float16* __restrict__ WT,
                                         int K, int N, int tile, float (*tls)[33], int tid) {
  int ntn = N >> 5;
  int nt = tile % ntn, kt = tile / ntn;
  int k0 = kt * 32, n0 = nt * 32;
  int tx = tid & 31, ty = tid >> 5;
#pragma unroll
  for (int p = 0; p < 4; p++) tls[ty + p * 8][tx] = W[(size_t)(k0 + ty + p * 8) * N + n0 + tx];
  __syncthreads();
#pragma unroll
  for (int p = 0; p < 4; p++) {
    int n = ty + p * 8;
    WT[(size_t)(n0 + n) * K + k0 + tx] = (_Float16)tls[tx][n];
  }
}

__global__ __launch_bounds__(256) void prep_kernel(
    const float* __restrict__ x, const float* __restrict__ Wq, const float* __restrict__ Wk,
    const float* __restrict__ Wv, const float* __restrict__ Wo, const float* __restrict__ Wr,
    float* __restrict__ pe_raw, unsigned* __restrict__ gmax, _Float16* __restrict__ xb,
    _Float16* __restrict__ WTqkv, _Float16* __restrict__ WoT, _Float16* __restrict__ WrT) {
  __shared__ float tls[32][33];
  int blk = blockIdx.x, tid = threadIdx.x;
  if (blk < PF_B) {
    int j = blk >> 4;
    int pos = (blk & 15) * 256 + tid;
    float prob = 0.0f;
    if (pos < NPOS) {
      float ap = fabsf((float)(pos - (SEQ - 1)));
      float hl = exp2f(3.0f + 8.0f * (float)j / 31.0f);
      float fe = exp2f(-ap / hl);
      float cw = exp2f((float)(j + 1)) - 1.0f;
      float fc = (cw > ap) ? 1.0f : 0.0f;
      float conc = 4.0f * (float)((j + 1) * (j + 1));
      float rate = (float)(j + 1) / 16.0f;
      float log_norm = lgammaf(conc) - conc * logf(rate);
      float log_un = (conc - 1.0f) * logf(ap) - rate * ap;
      prob = expf(log_un - log_norm) + 1e-8f;
      pe_raw[pos * 96 + j] = fe;
      pe_raw[pos * 96 + 32 + j] = fc;
      pe_raw[pos * 96 + 64 + j] = prob;
    }
    float m = prob;
#pragma unroll
    for (int off = 32; off > 0; off >>= 1) m = fmaxf(m, __shfl_down(m, off));
    __shared__ float red[4];
    if ((tid & 63) == 0) red[tid >> 6] = m;
    __syncthreads();
    if (tid == 0) {
      m = fmaxf(fmaxf(red[0], red[1]), fmaxf(red[2], red[3]));
      atomicMax(&gmax[j], __float_as_uint(m));
    }
  } else if (blk < PF_B + CAST_B) {
    int i = ((blk - PF_B) * 256 + tid) * 4;
    float4 v = *(const float4*)(x + i);
    _Float16 o[4] = {(_Float16)v.x, (_Float16)v.y, (_Float16)v.z, (_Float16)v.w};
    *(unsigned long long*)(xb + i) = *(const unsigned long long*)o;
  } else if (blk < PF_B + CAST_B + TWQ_B) {
    twc_tile(Wq, WTqkv + 0 * (size_t)CDIM, CDIM, HDK, blk - (PF_B + CAST_B), tls, tid);
  } else if (blk < PF_B + CAST_B + TWQ_B + TWK_B) {
    twc_tile(Wk, WTqkv + 512 * (size_t)CDIM, CDIM, HDK, blk - (PF_B + CAST_B + TWQ_B), tls, tid);
  } else if (blk < PF_B + CAST_B + TWQ_B + TWK_B + TWV_B) {
    twc_tile(Wv, WTqkv + 1024 * (size_t)CDIM, CDIM, HDV, blk - (PF_B + CAST_B + TWQ_B + TWK_B), tls, tid);
  } else if (blk < PF_B + CAST_B + TWQ_B + TWK_B + TWV_B + TWO_B) {
    twc_tile(Wo, WoT, CDIM, HDV, blk - (PF_B + CAST_B + TWQ_B + TWK_B + TWV_B), tls, tid);
  } else {
    twc_tile(Wr, WrT, 192, HDK, blk - (PF_B + CAST_B + TWQ_B + TWK_B + TWV_B + TWO_B), tls, tid);
  }
}

// ============ pe [4096][192] fp16: normalize gamma, apply sign-concat ============
__global__ __launch_bounds__(256) void pe_norm_kernel(const float* __restrict__ pe_raw,
                                                      const unsigned* __restrict__ gmax,
                                                      _Float16* __restrict__ pe_h) {
  int idx = blockIdx.x * 256 + threadIdx.x;  // over 4096*96
  int pos = idx / 96, f = idx - pos * 96;
  float val = 0.0f, sval = 0.0f;
  if (pos < NPOS) {
    val = pe_raw[pos * 96 + f];
    if (f >= 64) val *= 1.0f / __uint_as_float(gmax[f - 64]);
    float sgn = (pos > SEQ - 1) ? 1.0f : ((pos < SEQ - 1) ? -1.0f : 0.0f);
    sval = sgn * val;
  }
  pe_h[pos * 192 + f] = (_Float16)val;
  pe_h[pos * 192 + 96 + f] = (_Float16)sval;
}

// ================= fp16 MFMA GEMM, 128x128xBK32, XOR-swizzled LDS =================
// MODE 0 (QKV): c<512 -> qb*0.125 ; c<1024 -> kb[B,H,S,64] ; else vtb[B,H,192,S] PI-PERMUTED
// MODE 1 (RK):  rkb[(h*4096+pos)*64+d]
// MODE 2 (OUT): fp32 out + bias
template <int MODE>
__global__ __launch_bounds__(256, 2) void mfma_gemm(
    const _Float16* __restrict__ A, const _Float16* __restrict__ B,
    const float* __restrict__ bias, void* __restrict__ out0, void* __restrict__ out1,
    void* __restrict__ out2, int K) {
  __shared__ __align__(16) _Float16 As[128 * 32];
  __shared__ __align__(16) _Float16 Bs[128 * 32];
  const int tid = threadIdx.x;
  const int lane = tid & 63, l15 = lane & 15, quad = lane >> 4;
  const int wv = tid >> 6;
  const int wm = (wv & 1) * 64, wn = (wv >> 1) * 64;
  const int row0 = blockIdx.y * 128, col0 = blockIdx.x * 128;
  f4v acc[4][4];
#pragma unroll
  for (int i = 0; i < 4; i++)
#pragma unroll
    for (int j = 0; j < 4; j++) acc[i][j] = (f4v)0.0f;

  for (int k0 = 0; k0 < K; k0 += 32) {
    __syncthreads();
#pragma unroll
    for (int p = 0; p < 2; p++) {
      int idx = tid + p * 256;
      int rr = idx >> 2, sc = idx & 3;
      int gc = (sc ^ ((rr >> 1) & 3)) << 3;
      gl2lds16(A + (size_t)(row0 + rr) * K + k0 + gc, As + idx * 8);
      gl2lds16(B + (size_t)(col0 + rr) * K + k0 + gc, Bs + idx * 8);
    }
    __syncthreads();
    hf8v af[4], bfr[4];
#pragma unroll
    for (int t = 0; t < 4; t++) {
      int lrA = wm + t * 16 + l15;
      int lrB = wn + t * 16 + l15;
      af[t] = *(const hf8v*)(As + lrA * 32 + ((quad ^ ((lrA >> 1) & 3)) << 3));
      bfr[t] = *(const hf8v*)(Bs + lrB * 32 + ((quad ^ ((lrB >> 1) & 3)) << 3));
    }
#pragma unroll
    for (int mt = 0; mt < 4; mt++)
#pragma unroll
      for (int nt = 0; nt < 4; nt++)
        acc[mt][nt] = mfma16(af[mt], bfr[nt], acc[mt][nt]);
  }
#pragma unroll
  for (int mt = 0; mt < 4; mt++)
#pragma unroll
    for (int reg = 0; reg < 4; reg++) {
      int r = row0 + wm + mt * 16 + quad * 4 + reg;
      int bb = r >> 11, ss = r & (SEQ - 1);
#pragma unroll
      for (int nt = 0; nt < 4; nt++) {
        int c = col0 + wn + nt * 16 + l15;
        float vv = acc[mt][nt][reg];
        if (MODE == 0) {
          if (c < 512) {
            ((_Float16*)out0)[(size_t)r * HDK + c] = (_Float16)(vv * 0.125f);
          } else if (c < 1024) {
            int cc = c - 512, h = cc >> 6, d = cc & 63;
            ((_Float16*)out1)[(((size_t)bb * HN + h) * SEQ + ss) * 64 + d] = (_Float16)vv;
          } else {
            int cc = c - 1024, h = cc / DVC, e = cc - h * DVC;
            // pi-permute key within its 64-block: key k -> pos (k&15)*4 + ((k>>4)&3)
            int jp = (ss & ~63) | ((ss & 15) << 2) | ((ss >> 4) & 3);
            ((_Float16*)out2)[(((size_t)bb * HN + h) * DVC + e) * SEQ + jp] = (_Float16)vv;
          }
        } else if (MODE == 1) {
          int h = c >> 6, d = c & 63;
          ((_Float16*)out0)[((size_t)h * 4096 + r) * 64 + d] = (_Float16)vv;
        } else {
          ((float*)out0)[(size_t)r * HDV + c] = vv + bias[c];
        }
      }
    }
}

// ================= flash MFMA attention: LDS-staged K/V/RK, 2 barriers/iter ==============
// grid (16, SPLITKV?32:16); 4 waves, wave w owns q-rows [i0+32w, i0+32w+32) as 2 strips of 16
template <bool SPLITKV>
__global__ __launch_bounds__(256, 2) void attn_mfma(
    const _Float16* __restrict__ qb, const _Float16* __restrict__ kb,
    const _Float16* __restrict__ vtb, const _Float16* __restrict__ rkb,
    const float* __restrict__ rwb, const int* __restrict__ mask,
    _Float16* __restrict__ attn_out, float* __restrict__ Opart, float* __restrict__ ml) {
  __shared__ __align__(16) _Float16 Vts[192 * 64];   // 24576 B (pi-permuted keys)
  __shared__ __align__(16) _Float16 RKs[192 * 64];   // 24576 B
  __shared__ __align__(16) _Float16 Kts[64 * 64];    //  8192 B
  __shared__ __align__(16) _Float16 Pbs[128 * PSTR]; // 18432 B, wave-private (NOT aliased)
  // total 75776 B -> 2 blocks/CU

  const int i0 = blockIdx.x * 128;
  const int by = blockIdx.y;
  const int bh = SPLITKV ? (by & 15) : by;
  const int half = SPLITKV ? (by >> 4) : 0;
  const int b = bh >> 3, h = bh & 7;
  const int tid = threadIdx.x;
  const int wv = tid >> 6, lane = tid & 63;
  const int l15 = lane & 15, quad = lane >> 4;

  // Q A-fragments, 2 strips (held in VGPRs across all key tiles)
  hf8v qf[2][2], qbf[2][2];
#pragma unroll
  for (int s = 0; s < 2; s++) {
    int qrow = i0 + wv * 32 + s * 16 + l15;
    const _Float16* qp = qb + (size_t)(b * SEQ + qrow) * HDK + h * 64;
#pragma unroll
    for (int kc = 0; kc < 2; kc++) {
      hf8v qv = *(const hf8v*)(qp + kc * 32 + quad * 8);
      qf[s][kc] = qv;
      hf8v t;
#pragma unroll
      for (int j = 0; j < 8; j++)
        t[j] = (_Float16)((float)qv[j] + rwb[h * 64 + kc * 32 + quad * 8 + j]);
      qbf[s][kc] = t;
    }
  }

  f4v Of[2][12];
#pragma unroll
  for (int s = 0; s < 2; s++)
#pragma unroll
    for (int se = 0; se < 12; se++) Of[s][se] = (f4v)0.0f;
  float m_i[2][4] = {{-INFINITY, -INFINITY, -INFINITY, -INFINITY},
                     {-INFINITY, -INFINITY, -INFINITY, -INFINITY}};
  float l_i[2][4] = {{0.f, 0.f, 0.f, 0.f}, {0.f, 0.f, 0.f, 0.f}};  // per-lane partials

  const int j0beg = SPLITKV ? half * (SEQ / 2) : 0;
  const int j0end = SPLITKV ? j0beg + SEQ / 2 : SEQ;

  for (int j0 = j0beg; j0 < j0end; j0 += 64) {
    __syncthreads();  // (a) prior-tile readers done before staging overwrites
    {
      const int U0 = j0 - i0 + 1920;  // 192-row RK window base, in [0, 3904]
#pragma unroll
      for (int r = 0; r < 2; r++) {
        int idx = tid + r * 256, row = idx >> 3, sc = idx & 7;
        gl2lds16(kb + ((size_t)bh * SEQ + j0 + row) * 64 + ((sc ^ (row & 7)) << 3), Kts + idx * 8);
      }
#pragma unroll
      for (int r = 0; r < 6; r++) {
        int idx = tid + r * 256, row = idx >> 3, sc = idx & 7;
        gl2lds16(vtb + ((size_t)bh * DVC + row) * SEQ + j0 + ((sc ^ (row & 7)) << 3), Vts + idx * 8);
      }
#pragma unroll
      for (int r = 0; r < 6; r++) {
        int idx = tid + r * 256, row = idx >> 3, sc = idx & 7;
        gl2lds16(rkb + ((size_t)h * 4096 + U0 + row) * 64 + ((sc ^ (row & 7)) << 3), RKs + idx * 8);
      }
    }
    // mask via VMEM (not LDS): 4 scalar loads, issued before the barrier wait
    float mv[4];
#pragma unroll
    for (int st = 0; st < 4; st++)
      mv[st] = mask[b * SEQ + j0 + st * 16 + l15] ? 0.f : -1e9f;
    __syncthreads();  // (b) DMA drained -> LDS ready

#pragma unroll
    for (int s = 0; s < 2; s++) {
      // content logits
      f4v Sf[4];
#pragma unroll
      for (int st = 0; st < 4; st++) {
        Sf[st] = (f4v)0.0f;
#pragma unroll
        for (int kc = 0; kc < 2; kc++) {
          int row = st * 16 + l15;
          hf8v kf = *(const hf8v*)(Kts + row * 64 + ((((kc << 2) | quad) ^ (row & 7)) << 3));
          Sf[st] = mfma16(qf[s][kc], kf, Sf[st]);
        }
      }
      // rel logits over 80-row window
      f4v Rf[5];
      const int tb = 112 - 32 * wv - 16 * s;
#pragma unroll
      for (int u = 0; u < 5; u++) {
        Rf[u] = (f4v)0.0f;
#pragma unroll
        for (int kc = 0; kc < 2; kc++) {
          int row = tb + u * 16 + l15;
          hf8v rf = *(const hf8v*)(RKs + row * 64 + ((((kc << 2) | quad) ^ (row & 7)) << 3));
          Rf[u] = mfma16(qbf[s][kc], rf, Rf[u]);
        }
      }
      // band extraction via bpermute: S[r][c] += R[r][c-r+15]
#pragma unroll
      for (int reg = 0; reg < 4; reg++) {
        int delta = l15 - (quad << 2) - reg + 15;  // [0,30]
        int srcl = (quad << 4) | (delta & 15);
        float sh0 = __shfl(Rf[0][reg], srcl, 64);
        float sh1 = __shfl(Rf[1][reg], srcl, 64);
        float sh2 = __shfl(Rf[2][reg], srcl, 64);
        float sh3 = __shfl(Rf[3][reg], srcl, 64);
        float sh4 = __shfl(Rf[4][reg], srcl, 64);
        bool hib = delta >= 16;
        Sf[0][reg] += (hib ? sh1 : sh0) + mv[0];
        Sf[1][reg] += (hib ? sh2 : sh1) + mv[1];
        Sf[2][reg] += (hib ? sh3 : sh2) + mv[2];
        Sf[3][reg] += (hib ? sh4 : sh3) + mv[3];
      }
      // online softmax; P packed b64 into pi-slots (slot l15*4+st <-> key st*16+l15)
#pragma unroll
      for (int reg = 0; reg < 4; reg++) {
        float t = fmaxf(fmaxf(Sf[0][reg], Sf[1][reg]), fmaxf(Sf[2][reg], Sf[3][reg]));
        t = fmaxf(t, __shfl_xor(t, 1));
        t = fmaxf(t, __shfl_xor(t, 2));
        t = fmaxf(t, __shfl_xor(t, 4));
        t = fmaxf(t, __shfl_xor(t, 8));
        float mn = fmaxf(m_i[s][reg], t);
        float alpha = __expf(m_i[s][reg] - mn);
        m_i[s][reg] = mn;
        if (__ballot(alpha != 1.0f)) {
          l_i[s][reg] *= alpha;
#pragma unroll
          for (int se = 0; se < 12; se++) Of[s][se][reg] *= alpha;
        }
        hf4v pv;
        float rs = 0.f;
#pragma unroll
        for (int st = 0; st < 4; st++) {
          float p = __expf(Sf[st][reg] - mn);
          rs += p;
          pv[st] = (_Float16)p;
        }
        l_i[s][reg] += rs;  // per-lane partial; row-reduce in epilogue
        *(hf4v*)(Pbs + (size_t)(wv * 32 + s * 16 + quad * 4 + reg) * PSTR + l15 * 4) = pv;
      }
    }

    // PV: P A-frags (wave-private LDS, in-order DS), V B-frags from Vts (pi-ordered keys)
    hf8v pa[2][2];
#pragma unroll
    for (int s = 0; s < 2; s++)
#pragma unroll
      for (int kc = 0; kc < 2; kc++)
        pa[s][kc] = *(const hf8v*)(Pbs + (size_t)(wv * 32 + s * 16 + l15) * PSTR +
                                   kc * 32 + quad * 8);
#pragma unroll
    for (int se = 0; se < 12; se++) {
#pragma unroll
      for (int kc = 0; kc < 2; kc++) {
        int row = se * 16 + l15;
        hf8v vf = *(const hf8v*)(Vts + row * 64 + ((((kc << 2) | quad) ^ (row & 7)) << 3));
        Of[0][se] = mfma16(pa[0][kc], vf, Of[0][se]);
        Of[1][se] = mfma16(pa[1][kc], vf, Of[1][se]);
      }
    }
  }

#pragma unroll
  for (int s = 0; s < 2; s++)
#pragma unroll
    for (int reg = 0; reg < 4; reg++) {
      float ls = l_i[s][reg];
      ls += __shfl_xor(ls, 1);
      ls += __shfl_xor(ls, 2);
      ls += __shfl_xor(ls, 4);
      ls += __shfl_xor(ls, 8);
      int row = i0 + wv * 32 + s * 16 + quad * 4 + reg;
      int rg = b * SEQ + row;
      if constexpr (SPLITKV) {
        float* Op = Opart + ((size_t)(half * 4096 + rg)) * HDV + h * DVC;
#pragma unroll
        for (int se = 0; se < 12; se++) Op[se * 16 + l15] = Of[s][se][reg];
        if (l15 == 0) {
          size_t mlb = (((size_t)half * 4096 + rg) * HN + h) * 2;
          ml[mlb] = m_i[s][reg];
          ml[mlb + 1] = ls;
        }
      } else {
        float inv = 1.0f / ls;
        size_t base2 = (size_t)rg * HDV + h * DVC;
#pragma unroll
        for (int se = 0; se < 12; se++)
          attn_out[base2 + se * 16 + l15] = (_Float16)(Of[s][se][reg] * inv);
      }
    }
}

// ================= combine the two KV halves =================
__global__ __launch_bounds__(256) void combine_kernel(const float* __restrict__ Opart,
                                                      const float* __restrict__ ml,
                                                      _Float16* __restrict__ attn_out) {
  int i4 = blockIdx.x * 256 + threadIdx.x;  // over 4096*384
  int rg = i4 / 384, c4 = (i4 - rg * 384) * 4;
  int h = c4 / DVC;
  size_t mlb0 = ((size_t)rg * HN + h) * 2;
  size_t mlb1 = (((size_t)4096 + rg) * HN + h) * 2;
  float m0 = ml[mlb0], l0 = ml[mlb0 + 1];
  float m1 = ml[mlb1], l1 = ml[mlb1 + 1];
  float M = fmaxf(m0, m1);
  float w0 = __expf(m0 - M), w1 = __expf(m1 - M);
  float inv = 1.0f / (l0 * w0 + l1 * w1);
  float4 O0 = *(const float4*)(Opart + (size_t)rg * HDV + c4);
  float4 O1 = *(const float4*)(Opart + ((size_t)4096 + rg) * HDV + c4);
  _Float16 o[4] = {(_Float16)((O0.x * w0 + O1.x * w1) * inv),
                   (_Float16)((O0.y * w0 + O1.y * w1) * inv),
                   (_Float16)((O0.z * w0 + O1.z * w1) * inv),
                   (_Float16)((O0.w * w0 + O1.w * w1) * inv)};
  *(unsigned long long*)(attn_out + (size_t)rg * HDV + c4) = *(const unsigned long long*)o;
}

extern "C" void kernel_launch(void* const* d_in, const int* in_sizes, int n_in,
                              void* d_out, int out_size, void* d_ws, size_t ws_size,
                              hipStream_t stream) {
  const float* x    = (const float*)d_in[0];
  const int*   mask = (const int*)d_in[1];
  const float* Wq   = (const float*)d_in[2];
  const float* Wk   = (const float*)d_in[3];
  const float* Wv   = (const float*)d_in[4];
  const float* Wr   = (const float*)d_in[5];
  const float* rwb  = (const float*)d_in[6];
  const float* Wo   = (const float*)d_in[7];
  const float* bo   = (const float*)d_in[8];
  float* out = (float*)d_out;

  char* wsb = (char*)d_ws;
  size_t o = 0;
  auto al = [](size_t v) { return (v + 255) & ~(size_t)255; };
#define CARVE(ptr_t, name, bytes) ptr_t name = (ptr_t)(wsb + o); o = al(o + (bytes));
  CARVE(float*, pe_raw, (size_t)4096 * 96 * 4)
  CARVE(unsigned*, gmax, 128)
  CARVE(_Float16*, pe_h, (size_t)4096 * 192 * 2)
  CARVE(_Float16*, WrT, (size_t)HDK * 192 * 2)
  CARVE(_Float16*, xb, (size_t)BN * SEQ * CDIM * 2)
  CARVE(_Float16*, WTqkv, (size_t)2560 * CDIM * 2)
  CARVE(_Float16*, WoT, (size_t)HDV * CDIM * 2)
  CARVE(_Float16*, qb, (size_t)BN * SEQ * HDK * 2)
  CARVE(_Float16*, kb, (size_t)BN * SEQ * HDK * 2)
  CARVE(_Float16*, vtb, (size_t)BN * SEQ * HDV * 2)
  CARVE(_Float16*, rkb, (size_t)HN * 4096 * 64 * 2)
  _Float16* attnh = xb;  // xb dead after QKV gemm -> safe alias
  CARVE(float*, Opart, (size_t)2 * 4096 * HDV * 4)
  CARVE(float*, ml, (size_t)2 * 4096 * HN * 2 * 4)
  bool dosplit = (o <= ws_size);

  hipMemsetAsync(gmax, 0, 32 * sizeof(unsigned), stream);
  prep_kernel<<<PREP_BLOCKS, 256, 0, stream>>>(x, Wq, Wk, Wv, Wo, Wr, pe_raw, gmax, xb,
                                               WTqkv, WoT, WrT);
  pe_norm_kernel<<<4096 * 96 / 256, 256, 0, stream>>>(pe_raw, gmax, pe_h);
  mfma_gemm<0><<<dim3(2560 / 128, BN * SEQ / 128), 256, 0, stream>>>(
      xb, WTqkv, nullptr, qb, kb, vtb, CDIM);
  mfma_gemm<1><<<dim3(HDK / 128, 4096 / 128), 256, 0, stream>>>(
      pe_h, WrT, nullptr, rkb, nullptr, nullptr, 192);
  if (dosplit) {
    attn_mfma<true><<<dim3(SEQ / 128, 32), 256, 0, stream>>>(qb, kb, vtb, rkb, rwb, mask,
                                                             attnh, Opart, ml);
    combine_kernel<<<4096 * 384 / 256, 256, 0, stream>>>(Opart, ml, attnh);
  } else {
    attn_mfma<false><<<dim3(SEQ / 128, 16), 256, 0, stream>>>(qb, kb, vtb, rkb, rwb, mask,
                                                              attnh, nullptr, nullptr);
  }
  mfma_gemm<2><<<dim3(HDV / 128, BN * SEQ / 128), 256, 0, stream>>>(
      attnh, WoT, bo, out, nullptr, nullptr, CDIM);
}